// Round 12
// baseline (11376.661 us; speedup 1.0000x reference)
//
#include <hip/hip_runtime.h>
#include <cfloat>
#include <cstdint>

#define N_PTS 16384
#define KNN_K 16
#define KNN_TILE 512
#define CERT_EPS 3e-6f

typedef unsigned long long u64;

// ---------------------------------------------------------------------------
// FPS shared-memory block. Single-slot winner state is race-free by strict
// barrier alternation (writes and reads separated by barrier1/barrier2; next
// iteration's writes ordered behind the following barrier1).
// ---------------------------------------------------------------------------
struct FpsSmem {
    float2 sxy[N_PTS];          // x,y coords for the P=16 stage (128 KB)
    u64 wkey[16];               // per-wave packed (m1 bits << 32) | ~g
    float ws2[16];              // per-wave exact second value
    float4 wxyz[16];            // per-wave winning-point xyz payload
    u64 winkey;                 // merged global winner key
    int winsrc;                 // wave index holding the winning payload
    int fbflag;                 // fallback flag (exact global M2 >= thr)
    int cand_idx[64];
    int cand_cnt;
    int more_flag;
    double red_d[16];
};

__device__ __forceinline__ float keyf(u64 k) {
    return __uint_as_float((unsigned)(k >> 32));
}

// wave64 max-reduce on the VALU pipe via DPP (values >= 0; bound_ctrl zeros
// invalid lanes). Result valid in lane 63. Validated in R11 (absmax 0).
__device__ __forceinline__ float wave_max_f32(float x) {
    x = fmaxf(x, __int_as_float(__builtin_amdgcn_update_dpp(
                     0, __float_as_int(x), 0x111, 0xf, 0xf, true)));  // row_shr:1
    x = fmaxf(x, __int_as_float(__builtin_amdgcn_update_dpp(
                     0, __float_as_int(x), 0x112, 0xf, 0xf, true)));  // row_shr:2
    x = fmaxf(x, __int_as_float(__builtin_amdgcn_update_dpp(
                     0, __float_as_int(x), 0x114, 0xf, 0xf, true)));  // row_shr:4
    x = fmaxf(x, __int_as_float(__builtin_amdgcn_update_dpp(
                     0, __float_as_int(x), 0x118, 0xf, 0xf, true)));  // row_shr:8
    x = fmaxf(x, __int_as_float(__builtin_amdgcn_update_dpp(
                     0, __float_as_int(x), 0x142, 0xf, 0xf, true)));  // row_bcast:15
    x = fmaxf(x, __int_as_float(__builtin_amdgcn_update_dpp(
                     0, __float_as_int(x), 0x143, 0xf, 0xf, true)));  // row_bcast:31
    return x;
}

// ---------------------------------------------------------------------------
// FPS v11 body: T=1024 threads, P = n/T pts/thread, ownership g = tid + q*T.
// REG=true (P<=4): xyz fully register-resident, scan does NO LDS reads.
// REG=false (P=16): xy in LDS (float2, conflict-free), z in registers.
// Scan numerics bitwise identical to validated R5-R11. Tail: DPP wave argmax
// + exact wave second (replace-winner trick) + per-wave xyz payload; wave0
// 4-step butterfly merge carrying src => EXACT global M2; winner xyz reaches
// all threads via one LDS broadcast (no global load on the critical path).
// Fallback iff M2 >= thr — the validated criterion. fp64 fallback verbatim.
// ---------------------------------------------------------------------------
template <int P, bool IND, bool REG>
__device__ __forceinline__ void fps_body(FpsSmem& sm, const float* __restrict__ pts,
                                         const int* __restrict__ idx,
                                         int n_out, int* __restrict__ fi) {
    constexpr int T = 1024;
    constexpr int NW = T / 64;
    const int tid = threadIdx.x;
    const int wave = tid >> 6, lane = tid & 63;

    __syncthreads();  // guard smem reuse against the previous stage's reads

    float xr[REG ? P : 1], yr[REG ? P : 1];
    float zr[P], c[P];
#pragma unroll
    for (int q = 0; q < P; ++q) {
        const int g = tid + q * T;
        const int gg = IND ? idx[g] : g;
        float x = pts[gg * 3 + 0];
        float y = pts[gg * 3 + 1];
        zr[q] = pts[gg * 3 + 2];
        if constexpr (REG) {
            xr[q] = x;
            yr[q] = y;
        } else {
            sm.sxy[g] = make_float2(x, y);
        }
        c[q] = FLT_MAX;
    }
    const int g0 = IND ? idx[0] : 0;
    float sx = pts[g0 * 3 + 0], sy = pts[g0 * 3 + 1], sz = pts[g0 * 3 + 2];
    if (tid == 0) fi[0] = g0;
    __syncthreads();

    for (int it = 1; it < n_out; ++it) {
        // ---- scan: fused min-update + per-thread top-2 (validated, verbatim) ----
        float m1 = -1.0f, m2 = -1.0f;
        int g1 = 0x7fffffff;
#pragma unroll
        for (int q = 0; q < P; ++q) {
            float px, py;
            if constexpr (REG) {
                px = xr[q]; py = yr[q];
            } else {
                float2 xy = sm.sxy[tid + q * T];
                px = xy.x; py = xy.y;
            }
            float dx = px - sx, dy = py - sy, dz = zr[q] - sz;
            float t = fmaf(dx, dx, fmaf(dy, dy, dz * dz));
            float nc = fminf(c[q], t);
            c[q] = nc;
            bool gt = nc > m1;
            m2 = fmaxf(m2, fminf(nc, m1));
            m1 = fmaxf(m1, nc);
            g1 = gt ? (tid + q * T) : g1;
        }

        // ---- wave-level: DPP argmax + exact wave second + xyz payload ----
        float wm = wave_max_f32(m1);
        float wmax = __shfl(wm, 63);
        u64 bal = __ballot(m1 == wmax);
        int w0 = __ffsll((unsigned long long)bal) - 1;  // first lane at wave max
        float m1p = (lane == w0) ? fmaxf(m2, 0.0f) : m1;
        float s2r = wave_max_f32(m1p);                  // lane63: exact wave 2nd
        if (lane == w0) {
            const int qw = (g1 - tid) / T;
            float wx = 0.0f, wy = 0.0f, wzv = 0.0f;
            if constexpr (REG) {
#pragma unroll
                for (int q = 0; q < P; ++q)
                    if (q == qw) { wx = xr[q]; wy = yr[q]; wzv = zr[q]; }
            } else {
                float2 xy = sm.sxy[g1];
                wx = xy.x; wy = xy.y;
#pragma unroll
                for (int q = 0; q < P; ++q)
                    if (q == qw) wzv = zr[q];
            }
            sm.wxyz[wave] = make_float4(wx, wy, wzv, 0.0f);
        }
        int wg = __shfl(g1, w0);
        if (lane == 63) {
            sm.wkey[wave] = ((u64)__float_as_uint(wmax) << 32) |
                            (u64)(~(unsigned)wg);
            sm.ws2[wave] = s2r;
        }
        __syncthreads();  // barrier1

        // ---- block-level: wave0 4-step butterfly (keys unique; src payload) ----
        if (wave == 0) {
            u64 k = (lane < 16) ? sm.wkey[lane] : 0ull;
            float s = (lane < 16) ? sm.ws2[lane] : 0.0f;
            int src = lane & 15;
#pragma unroll
            for (int off = 8; off; off >>= 1) {
                u64 ok = __shfl_xor(k, off);
                float os = __shfl_xor(s, off);
                int osrc = __shfl_xor(src, off);
                if (ok == k) {          // only possible for idle zero keys
                    s = fmaxf(s, os);
                } else if (ok > k) {
                    s = fmaxf(os, keyf(k));
                    k = ok;
                    src = osrc;
                } else {
                    s = fmaxf(s, keyf(ok));
                }
            }
            if (lane == 0) {
                const float M1 = keyf(k);
                const float thr = M1 - M1 * CERT_EPS;
                sm.winkey = k;
                sm.winsrc = src;
                sm.fbflag = (s >= thr) ? 1 : 0;  // s = EXACT global second
            }
        }
        __syncthreads();  // barrier2

        // ---- broadcast winner via payload; rare exact fp64 fallback ----
        const u64 wk = sm.winkey;
        int winner = (int)(~(unsigned)wk);
        float4 wv = sm.wxyz[sm.winsrc];
        const float M1a = keyf(wk);
        const float thr = M1a - M1a * CERT_EPS;
        if (sm.fbflag) {
            // ---- cooperative exact fp64 fallback (uniform branch, verbatim) ----
            unsigned miss = 0;
#pragma unroll
            for (int q = 0; q < P; ++q)
                if (c[q] >= thr) miss |= (1u << q);
            double BD = -1.0;
            int BG = 0x7fffffff;
            for (;;) {
                if (tid == 0) { sm.cand_cnt = 0; sm.more_flag = 0; }
                __syncthreads();
#pragma unroll
                for (int q = 0; q < P; ++q) {
                    if (miss & (1u << q)) {
                        int slot = atomicAdd(&sm.cand_cnt, 1);
                        if (slot < 64) {
                            sm.cand_idx[slot] = tid + q * T;
                            miss &= ~(1u << q);
                        } else {
                            sm.more_flag = 1;
                        }
                    }
                }
                __syncthreads();
                int ncand = sm.cand_cnt;
                if (ncand > 64) ncand = 64;
                for (int ci = 0; ci < ncand; ++ci) {
                    const int g = sm.cand_idx[ci];
                    const int gg = IND ? idx[g] : g;
                    const double qx = (double)pts[gg * 3 + 0];
                    const double qy = (double)pts[gg * 3 + 1];
                    const double qz = (double)pts[gg * 3 + 2];
                    double dmin = DBL_MAX;
                    for (int i = tid; i < it; i += T) {
                        const int h = fi[i];  // original index, any stage
                        double ddx = qx - (double)pts[h * 3 + 0];
                        double ddy = qy - (double)pts[h * 3 + 1];
                        double ddz = qz - (double)pts[h * 3 + 2];
                        double dd = ddx * ddx + ddy * ddy + ddz * ddz;
                        dmin = (dd < dmin) ? dd : dmin;
                    }
                    for (int off = 32; off; off >>= 1) {
                        double od = __shfl_xor(dmin, off);
                        dmin = (od < dmin) ? od : dmin;
                    }
                    if (lane == 0) sm.red_d[wave] = dmin;
                    __syncthreads();
                    double dall = sm.red_d[0];
#pragma unroll
                    for (int w = 1; w < NW; ++w) dall = (sm.red_d[w] < dall) ? sm.red_d[w] : dall;
                    if (dall > BD || (dall == BD && g < BG)) { BD = dall; BG = g; }
                    __syncthreads();
                }
                int mf = sm.more_flag;
                __syncthreads();
                if (!mf) break;
            }
            winner = BG;
            const int wgf = IND ? idx[winner] : winner;
            wv = make_float4(pts[wgf * 3 + 0], pts[wgf * 3 + 1],
                             pts[wgf * 3 + 2], 0.0f);
        }
        if (tid == 0) fi[it] = IND ? idx[winner] : winner;
        sx = wv.x; sy = wv.y; sz = wv.z;
    }
}

// ---------------------------------------------------------------------------
// Fused KNN + EdgeConv body: 1024 threads = 16 waves = 16 query points.
// Per-wave fp64-exact top-16 (verbatim validated numerics), edgeconv inline.
// ---------------------------------------------------------------------------
struct KnnSmem {
    float sx[KNN_TILE], sy[KNN_TILE], sz[KNN_TILE];
    float w1[6 * 64], b1v[64], w2[64 * 64], b2v[64];
};

__device__ __forceinline__ void knn_edge_body(
    KnnSmem& sm, const float* __restrict__ pts,
    const float* __restrict__ ew1, const float* __restrict__ eb1,
    const float* __restrict__ ew2, const float* __restrict__ eb2,
    float* __restrict__ feats, int qb) {
    for (int t = threadIdx.x; t < 6 * 64; t += 1024) sm.w1[t] = ew1[t];
    for (int t = threadIdx.x; t < 64; t += 1024) { sm.b1v[t] = eb1[t]; sm.b2v[t] = eb2[t]; }
    for (int t = threadIdx.x; t < 64 * 64; t += 1024) sm.w2[t] = ew2[t];

    const int wave = threadIdx.x >> 6;
    const int lane = threadIdx.x & 63;
    const int qi = qb * 16 + wave;
    const double qxd = (double)pts[qi * 3 + 0];
    const double qyd = (double)pts[qi * 3 + 1];
    const double qzd = (double)pts[qi * 3 + 2];

    double ld[16];
    int li[16];
#pragma unroll
    for (int s = 0; s < 16; ++s) { ld[s] = DBL_MAX; li[s] = 0x7fffffff; }
    double md = DBL_MAX; int mj = 0x7fffffff; int mslot = 0;

    for (int t0 = 0; t0 < N_PTS; t0 += KNN_TILE) {
        __syncthreads();
        for (int t = threadIdx.x; t < KNN_TILE; t += 1024) {
            sm.sx[t] = pts[(t0 + t) * 3 + 0];
            sm.sy[t] = pts[(t0 + t) * 3 + 1];
            sm.sz[t] = pts[(t0 + t) * 3 + 2];
        }
        __syncthreads();
#pragma unroll
        for (int m = 0; m < KNN_TILE / 64; ++m) {
            const int cc = lane + m * 64;
            const int j = t0 + cc;
            if (j == qi) continue;  // diagonal excluded (d=inf in reference)
            double dx = qxd - (double)sm.sx[cc];
            double dy = qyd - (double)sm.sy[cc];
            double dz = qzd - (double)sm.sz[cc];
            double dd = dx * dx + dy * dy + dz * dz;
            if (dd < md || (dd == md && j < mj)) {
#pragma unroll
                for (int s = 0; s < 16; ++s)
                    if (s == mslot) { ld[s] = dd; li[s] = j; }
                md = -1.0; mj = -1; mslot = 0;
#pragma unroll
                for (int s = 0; s < 16; ++s) {
                    bool g = (ld[s] > md) || (ld[s] == md && li[s] > mj);
                    if (g) { md = ld[s]; mj = li[s]; mslot = s; }
                }
            }
        }
    }

    const float xi = pts[qi * 3], yi = pts[qi * 3 + 1], zi = pts[qi * 3 + 2];
    float acc = -FLT_MAX;
    for (int r = 0; r < KNN_K; ++r) {
        double cd = DBL_MAX; int cj = 0x7fffffff; int cs = 0;
#pragma unroll
        for (int s = 0; s < 16; ++s) {
            bool l = (ld[s] < cd) || (ld[s] == cd && li[s] < cj);
            if (l) { cd = ld[s]; cj = li[s]; cs = s; }
        }
        double wd = cd; int wj = cj;
        for (int off = 32; off; off >>= 1) {
            double od = __shfl_xor(wd, off);
            int oj = __shfl_xor(wj, off);
            if (od < wd || (od == wd && oj < wj)) { wd = od; wj = oj; }
        }
        if (cd == wd && cj == wj) {
#pragma unroll
            for (int s = 0; s < 16; ++s)
                if (s == cs) { ld[s] = DBL_MAX; li[s] = 0x7fffffff; }
        }
        const float xj = pts[wj * 3], yj = pts[wj * 3 + 1], zj = pts[wj * 3 + 2];
        const float f3 = xj - xi, f4 = yj - yi, f5 = zj - zi;
        float h1 = sm.b1v[lane];
        h1 = fmaf(xi, sm.w1[0 * 64 + lane], h1);
        h1 = fmaf(yi, sm.w1[1 * 64 + lane], h1);
        h1 = fmaf(zi, sm.w1[2 * 64 + lane], h1);
        h1 = fmaf(f3, sm.w1[3 * 64 + lane], h1);
        h1 = fmaf(f4, sm.w1[4 * 64 + lane], h1);
        h1 = fmaf(f5, sm.w1[5 * 64 + lane], h1);
        h1 = fmaxf(h1, 0.0f);
        float h2 = sm.b2v[lane];
        for (int d = 0; d < 64; ++d)
            h2 = fmaf(__shfl(h1, d), sm.w2[d * 64 + lane], h2);
        acc = fmaxf(acc, h2);
    }
    feats[qi * 64 + lane] = acc;
}

// ---------------------------------------------------------------------------
// Mega kernel: block 0 chains fps0 -> fps1 -> fps2 (fi* = ORIGINAL indices)
// and writes sp0/sp1/sp2. Blocks 1..1024 = fused knn+edgeconv (hidden).
// ---------------------------------------------------------------------------
__global__ __launch_bounds__(1024)
void mega_kernel(const float* __restrict__ pts,
                 const float* __restrict__ ew1, const float* __restrict__ eb1,
                 const float* __restrict__ ew2, const float* __restrict__ eb2,
                 float* __restrict__ feats,
                 int* __restrict__ fi0, int* __restrict__ fi1, int* __restrict__ fi2,
                 float* __restrict__ sp0, float* __restrict__ sp1,
                 float* __restrict__ sp2) {
    __shared__ __align__(16) char raw[sizeof(FpsSmem)];
    if (blockIdx.x == 0) {
        FpsSmem& sm = *reinterpret_cast<FpsSmem*>(raw);
        fps_body<16, false, false>(sm, pts, nullptr, 4096, fi0);
        fps_body<4, true, true>(sm, pts, fi0, 1024, fi1);
        fps_body<1, true, true>(sm, pts, fi1, 256, fi2);
        __syncthreads();
        const int tid = threadIdx.x;
        for (int t = tid; t < 4096; t += 1024) {
            int g = fi0[t];
            sp0[t * 3 + 0] = pts[g * 3 + 0];
            sp0[t * 3 + 1] = pts[g * 3 + 1];
            sp0[t * 3 + 2] = pts[g * 3 + 2];
        }
        if (tid < 1024) {
            int g = fi1[tid];
            sp1[tid * 3 + 0] = pts[g * 3 + 0];
            sp1[tid * 3 + 1] = pts[g * 3 + 1];
            sp1[tid * 3 + 2] = pts[g * 3 + 2];
        }
        if (tid < 256) {
            int g = fi2[tid];
            sp2[tid * 3 + 0] = pts[g * 3 + 0];
            sp2[tid * 3 + 1] = pts[g * 3 + 1];
            sp2[tid * 3 + 2] = pts[g * 3 + 2];
        }
    } else {
        knn_edge_body(*reinterpret_cast<KnnSmem*>(raw), pts, ew1, eb1, ew2, eb2,
                      feats, blockIdx.x - 1);
    }
}

// ---------------------------------------------------------------------------
// Tail: all three MLPs in one launch (validated mlp numerics, verbatim).
// ---------------------------------------------------------------------------
__device__ __forceinline__ void mlp_body(
    const float* __restrict__ feats, const int* __restrict__ orig,
    const float* __restrict__ mw1, const float* __restrict__ mb1,
    const float* __restrict__ mw2, const float* __restrict__ mb2,
    float* __restrict__ outp, int pb) {
    __shared__ float sfl[64], h1l[128];
    const int t = threadIdx.x;
    for (int pl = 0; pl < 16; ++pl) {
        const int p = pb * 16 + pl;
        const int g = orig[p];
        if (t < 64) sfl[t] = feats[g * 64 + t];
        __syncthreads();
        if (t < 128) {
            float h = mb1[t];
            for (int dd = 0; dd < 64; ++dd)
                h = fmaf(sfl[dd], mw1[dd * 128 + t], h);
            h1l[t] = fmaxf(h, 0.0f);
        }
        __syncthreads();
        float o = mb2[t];
        for (int dd = 0; dd < 128; ++dd)
            o = fmaf(h1l[dd], mw2[dd * 256 + t], o);
        outp[p * 256 + t] = o;
        __syncthreads();
    }
}

__global__ __launch_bounds__(256) void tail_kernel(
    const float* __restrict__ feats,
    const int* __restrict__ fi0, const int* __restrict__ fi1,
    const int* __restrict__ fi2,
    const float* __restrict__ mw1, const float* __restrict__ mb1,
    const float* __restrict__ mw2, const float* __restrict__ mb2,
    float* __restrict__ out) {
    const int b = blockIdx.x;
    float* lf0 = out + 12288;
    float* lf1 = out + 1063936;
    float* lf2 = out + 1326848;
    if (b < 256) {
        mlp_body(feats, fi0, mw1 + 0 * 8192, mb1 + 0 * 128,
                 mw2 + 0 * 32768, mb2 + 0 * 256, lf0, b);
    } else if (b < 320) {
        mlp_body(feats, fi1, mw1 + 1 * 8192, mb1 + 1 * 128,
                 mw2 + 1 * 32768, mb2 + 1 * 256, lf1, b - 256);
    } else {
        mlp_body(feats, fi2, mw1 + 2 * 8192, mb1 + 2 * 128,
                 mw2 + 2 * 32768, mb2 + 2 * 256, lf2, b - 320);
    }
}

// ---------------------------------------------------------------------------
extern "C" void kernel_launch(void* const* d_in, const int* in_sizes, int n_in,
                              void* d_out, int out_size, void* d_ws, size_t ws_size,
                              hipStream_t stream) {
    const float* pts = (const float*)d_in[0];
    const float* ew1 = (const float*)d_in[1];
    const float* eb1 = (const float*)d_in[2];
    const float* ew2 = (const float*)d_in[3];
    const float* eb2 = (const float*)d_in[4];
    const float* mw1 = (const float*)d_in[5];  // (3,64,128)
    const float* mb1 = (const float*)d_in[6];  // (3,128)
    const float* mw2 = (const float*)d_in[7];  // (3,128,256)
    const float* mb2 = (const float*)d_in[8];  // (3,256)
    float* out = (float*)d_out;
    char* ws = (char*)d_ws;

    float* feats = (float*)(ws + 0);           // 16384*64*4 = 4 MB
    int* fi0 = (int*)(ws + 4194304);           // 4096 ints (original indices)
    int* fi1 = (int*)(ws + 4210688);           // 1024 ints (original indices)
    int* fi2 = (int*)(ws + 4214784);           // 256 ints  (original indices)

    float* sp0 = out + 0;
    float* sp1 = out + 1060864;
    float* sp2 = out + 1326080;

    mega_kernel<<<1 + N_PTS / 16, 1024, 0, stream>>>(pts, ew1, eb1, ew2, eb2, feats,
                                                     fi0, fi1, fi2, sp0, sp1, sp2);
    tail_kernel<<<336, 256, 0, stream>>>(feats, fi0, fi1, fi2, mw1, mb1, mw2, mb2, out);
}

// Round 14
// 9742.540 us; speedup vs baseline: 1.1677x; 1.1677x over previous
//
#include <hip/hip_runtime.h>
#include <cfloat>
#include <cstdint>

#define N_PTS 16384
#define KNN_K 16
#define KNN_TILE 512
#define CERT_EPS 3e-6f

// ---------------------------------------------------------------------------
// FPS shared-memory block (sized for the largest scale; reused by all three).
// ---------------------------------------------------------------------------
struct FpsSmem {
    float2 sxy[N_PTS];                  // x,y coords (z stays in registers)
    unsigned long long slots[2][16];    // packed argmax, tid&15-spread, parity dbuf
    int cw[2][16];                      // per-wave count of m1 >= thr
    int wf[2];                          // winner-thread m2 >= thr flag
    float4 win[2];                      // winner xyz broadcast
    int cand_idx[64];
    int cand_cnt;
    int more_flag;
    double red_d[16];
};

// ---------------------------------------------------------------------------
// FPS body (R9 configuration — best measured: 9.80 ms total): T=1024 threads,
// P pts/thread. IND=true -> coords are pts[idx[g]]; fi[] always receives
// ORIGINAL point indices. Scan numerics bitwise identical to validated R5+
// (certified fp32, direct form, per-thread top-2). Argmax: packed-key
// atomicMax spread over 16 LDS slots (tid&15). Winner thread publishes xyz
// between the two barriers (z from its own register). Certification:
// fallback iff (#threads m1>=thr) > 1 OR winner m2>=thr == validated M2>=thr.
// Cooperative exact fp64 fallback verbatim.
// ---------------------------------------------------------------------------
template <int P, bool IND>
__device__ __forceinline__ void fps_body(FpsSmem& sm, const float* __restrict__ pts,
                                         const int* __restrict__ idx,
                                         int n_out, int* __restrict__ fi) {
    constexpr int T = 1024;
    constexpr int NW = T / 64;
    const int tid = threadIdx.x;
    const int wave = tid >> 6, lane = tid & 63;

    __syncthreads();  // guard smem reuse against the previous stage's reads

    float zr[P], c[P];
#pragma unroll
    for (int q = 0; q < P; ++q) {
        const int g = tid + q * T;
        const int gg = IND ? idx[g] : g;
        float x = pts[gg * 3 + 0];
        float y = pts[gg * 3 + 1];
        zr[q] = pts[gg * 3 + 2];
        sm.sxy[g] = make_float2(x, y);
        c[q] = FLT_MAX;
    }
    if (tid < 32) sm.slots[tid >> 4][tid & 15] = 0ull;
    const int g0 = IND ? idx[0] : 0;
    float sx = pts[g0 * 3 + 0], sy = pts[g0 * 3 + 1], sz = pts[g0 * 3 + 2];
    if (tid == 0) fi[0] = g0;
    __syncthreads();

    for (int it = 1; it < n_out; ++it) {
        // fused min-update + per-thread top-2 (validated numerics, verbatim)
        float m1 = -1.0f, m2 = -1.0f;
        int g1 = 0x7fffffff;
#pragma unroll
        for (int q = 0; q < P; ++q) {
            float2 xy = sm.sxy[tid + q * T];
            float dx = xy.x - sx, dy = xy.y - sy, dz = zr[q] - sz;
            float t = fmaf(dx, dx, fmaf(dy, dy, dz * dz));
            float nc = fminf(c[q], t);
            c[q] = nc;
            bool gt = nc > m1;
            m2 = fmaxf(m2, fminf(nc, m1));
            m1 = fmaxf(m1, nc);
            g1 = gt ? (tid + q * T) : g1;
        }
        const int par = it & 1;
        unsigned long long key =
            ((unsigned long long)__float_as_uint(m1) << 32) |
            (unsigned long long)(~(unsigned)g1);
        atomicMax(&sm.slots[par][tid & 15], key);
        __syncthreads();
        unsigned long long best = sm.slots[par][0];
#pragma unroll
        for (int w = 1; w < 16; ++w) {
            unsigned long long v = sm.slots[par][w];
            if (v > best) best = v;
        }
        const float M1 = __uint_as_float((unsigned)(best >> 32));
        const int G1 = (int)(~(unsigned)best);
        if (tid < 16) sm.slots[par ^ 1][tid] = 0ull;  // reset other parity
        const float thr = M1 - M1 * CERT_EPS;
        unsigned long long bal = __ballot(m1 >= thr);
        if (lane == 0) sm.cw[par][wave] = __popcll(bal);
        if (g1 == G1) {  // exactly one thread (disjoint point ownership)
            sm.wf[par] = (m2 >= thr) ? 1 : 0;
            const int qw = (g1 - tid) / T;
            float zw = 0.0f;
#pragma unroll
            for (int q = 0; q < P; ++q)
                if (q == qw) zw = zr[q];
            float2 xy = sm.sxy[g1];
            sm.win[par] = make_float4(xy.x, xy.y, zw, 0.0f);
        }
        __syncthreads();
        int total = sm.cw[par][0];
#pragma unroll
        for (int w = 1; w < NW; ++w) total += sm.cw[par][w];
        int winner = G1;
        float4 wv = sm.win[par];
        if (total > 1 || sm.wf[par]) {
            // ---- cooperative exact fp64 fallback (uniform branch, verbatim) ----
            unsigned miss = 0;
#pragma unroll
            for (int q = 0; q < P; ++q)
                if (c[q] >= thr) miss |= (1u << q);
            double BD = -1.0;
            int BG = 0x7fffffff;
            for (;;) {
                if (tid == 0) { sm.cand_cnt = 0; sm.more_flag = 0; }
                __syncthreads();
#pragma unroll
                for (int q = 0; q < P; ++q) {
                    if (miss & (1u << q)) {
                        int slot = atomicAdd(&sm.cand_cnt, 1);
                        if (slot < 64) {
                            sm.cand_idx[slot] = tid + q * T;
                            miss &= ~(1u << q);
                        } else {
                            sm.more_flag = 1;
                        }
                    }
                }
                __syncthreads();
                int ncand = sm.cand_cnt;
                if (ncand > 64) ncand = 64;
                for (int ci = 0; ci < ncand; ++ci) {
                    const int g = sm.cand_idx[ci];
                    const int gg = IND ? idx[g] : g;
                    const double qx = (double)pts[gg * 3 + 0];
                    const double qy = (double)pts[gg * 3 + 1];
                    const double qz = (double)pts[gg * 3 + 2];
                    double dmin = DBL_MAX;
                    for (int i = tid; i < it; i += T) {
                        const int h = fi[i];  // original index, any stage
                        double ddx = qx - (double)pts[h * 3 + 0];
                        double ddy = qy - (double)pts[h * 3 + 1];
                        double ddz = qz - (double)pts[h * 3 + 2];
                        double dd = ddx * ddx + ddy * ddy + ddz * ddz;
                        dmin = (dd < dmin) ? dd : dmin;
                    }
                    for (int off = 32; off; off >>= 1) {
                        double od = __shfl_xor(dmin, off);
                        dmin = (od < dmin) ? od : dmin;
                    }
                    if (lane == 0) sm.red_d[wave] = dmin;
                    __syncthreads();
                    double dall = sm.red_d[0];
#pragma unroll
                    for (int w = 1; w < NW; ++w) dall = (sm.red_d[w] < dall) ? sm.red_d[w] : dall;
                    if (dall > BD || (dall == BD && g < BG)) { BD = dall; BG = g; }
                    __syncthreads();
                }
                int mf = sm.more_flag;
                __syncthreads();
                if (!mf) break;
            }
            winner = BG;
            float2 xy = sm.sxy[winner];
            const int wg = IND ? idx[winner] : winner;
            wv = make_float4(xy.x, xy.y, pts[wg * 3 + 2], 0.0f);
        }
        if (tid == 0) fi[it] = IND ? idx[winner] : winner;
        sx = wv.x; sy = wv.y; sz = wv.z;
    }
}

// ---------------------------------------------------------------------------
// Fused KNN + EdgeConv body: 1024 threads = 16 waves = 16 query points.
// Per-wave fp64-exact top-16 (verbatim validated numerics), edgeconv inline.
// ---------------------------------------------------------------------------
struct KnnSmem {
    float sx[KNN_TILE], sy[KNN_TILE], sz[KNN_TILE];
    float w1[6 * 64], b1v[64], w2[64 * 64], b2v[64];
};

__device__ __forceinline__ void knn_edge_body(
    KnnSmem& sm, const float* __restrict__ pts,
    const float* __restrict__ ew1, const float* __restrict__ eb1,
    const float* __restrict__ ew2, const float* __restrict__ eb2,
    float* __restrict__ feats, int qb) {
    for (int t = threadIdx.x; t < 6 * 64; t += 1024) sm.w1[t] = ew1[t];
    for (int t = threadIdx.x; t < 64; t += 1024) { sm.b1v[t] = eb1[t]; sm.b2v[t] = eb2[t]; }
    for (int t = threadIdx.x; t < 64 * 64; t += 1024) sm.w2[t] = ew2[t];

    const int wave = threadIdx.x >> 6;
    const int lane = threadIdx.x & 63;
    const int qi = qb * 16 + wave;
    const double qxd = (double)pts[qi * 3 + 0];
    const double qyd = (double)pts[qi * 3 + 1];
    const double qzd = (double)pts[qi * 3 + 2];

    double ld[16];
    int li[16];
#pragma unroll
    for (int s = 0; s < 16; ++s) { ld[s] = DBL_MAX; li[s] = 0x7fffffff; }
    double md = DBL_MAX; int mj = 0x7fffffff; int mslot = 0;

    for (int t0 = 0; t0 < N_PTS; t0 += KNN_TILE) {
        __syncthreads();
        for (int t = threadIdx.x; t < KNN_TILE; t += 1024) {
            sm.sx[t] = pts[(t0 + t) * 3 + 0];
            sm.sy[t] = pts[(t0 + t) * 3 + 1];
            sm.sz[t] = pts[(t0 + t) * 3 + 2];
        }
        __syncthreads();
#pragma unroll
        for (int m = 0; m < KNN_TILE / 64; ++m) {
            const int cc = lane + m * 64;
            const int j = t0 + cc;
            if (j == qi) continue;  // diagonal excluded (d=inf in reference)
            double dx = qxd - (double)sm.sx[cc];
            double dy = qyd - (double)sm.sy[cc];
            double dz = qzd - (double)sm.sz[cc];
            double dd = dx * dx + dy * dy + dz * dz;
            if (dd < md || (dd == md && j < mj)) {
#pragma unroll
                for (int s = 0; s < 16; ++s)
                    if (s == mslot) { ld[s] = dd; li[s] = j; }
                md = -1.0; mj = -1; mslot = 0;
#pragma unroll
                for (int s = 0; s < 16; ++s) {
                    bool g = (ld[s] > md) || (ld[s] == md && li[s] > mj);
                    if (g) { md = ld[s]; mj = li[s]; mslot = s; }
                }
            }
        }
    }

    const float xi = pts[qi * 3], yi = pts[qi * 3 + 1], zi = pts[qi * 3 + 2];
    float acc = -FLT_MAX;
    for (int r = 0; r < KNN_K; ++r) {
        double cd = DBL_MAX; int cj = 0x7fffffff; int cs = 0;
#pragma unroll
        for (int s = 0; s < 16; ++s) {
            bool l = (ld[s] < cd) || (ld[s] == cd && li[s] < cj);
            if (l) { cd = ld[s]; cj = li[s]; cs = s; }
        }
        double wd = cd; int wj = cj;
        for (int off = 32; off; off >>= 1) {
            double od = __shfl_xor(wd, off);
            int oj = __shfl_xor(wj, off);
            if (od < wd || (od == wd && oj < wj)) { wd = od; wj = oj; }
        }
        if (cd == wd && cj == wj) {
#pragma unroll
            for (int s = 0; s < 16; ++s)
                if (s == cs) { ld[s] = DBL_MAX; li[s] = 0x7fffffff; }
        }
        const float xj = pts[wj * 3], yj = pts[wj * 3 + 1], zj = pts[wj * 3 + 2];
        const float f3 = xj - xi, f4 = yj - yi, f5 = zj - zi;
        float h1 = sm.b1v[lane];
        h1 = fmaf(xi, sm.w1[0 * 64 + lane], h1);
        h1 = fmaf(yi, sm.w1[1 * 64 + lane], h1);
        h1 = fmaf(zi, sm.w1[2 * 64 + lane], h1);
        h1 = fmaf(f3, sm.w1[3 * 64 + lane], h1);
        h1 = fmaf(f4, sm.w1[4 * 64 + lane], h1);
        h1 = fmaf(f5, sm.w1[5 * 64 + lane], h1);
        h1 = fmaxf(h1, 0.0f);
        float h2 = sm.b2v[lane];
        for (int d = 0; d < 64; ++d)
            h2 = fmaf(__shfl(h1, d), sm.w2[d * 64 + lane], h2);
        acc = fmaxf(acc, h2);
    }
    feats[qi * 64 + lane] = acc;
}

// ---------------------------------------------------------------------------
// Mega kernel: block 0 chains fps0 -> fps1 -> fps2 (coords LDS-resident;
// fi* = ORIGINAL indices) and writes sp0/sp1/sp2. Blocks 1..1024 = fused
// knn+edgeconv (hidden under fps).
// ---------------------------------------------------------------------------
__global__ __launch_bounds__(1024)
void mega_kernel(const float* __restrict__ pts,
                 const float* __restrict__ ew1, const float* __restrict__ eb1,
                 const float* __restrict__ ew2, const float* __restrict__ eb2,
                 float* __restrict__ feats,
                 int* __restrict__ fi0, int* __restrict__ fi1, int* __restrict__ fi2,
                 float* __restrict__ sp0, float* __restrict__ sp1,
                 float* __restrict__ sp2) {
    __shared__ __align__(16) char raw[sizeof(FpsSmem)];
    if (blockIdx.x == 0) {
        FpsSmem& sm = *reinterpret_cast<FpsSmem*>(raw);
        fps_body<16, false>(sm, pts, nullptr, 4096, fi0);
        fps_body<4, true>(sm, pts, fi0, 1024, fi1);
        fps_body<1, true>(sm, pts, fi1, 256, fi2);
        __syncthreads();
        const int tid = threadIdx.x;
        for (int t = tid; t < 4096; t += 1024) {
            int g = fi0[t];
            sp0[t * 3 + 0] = pts[g * 3 + 0];
            sp0[t * 3 + 1] = pts[g * 3 + 1];
            sp0[t * 3 + 2] = pts[g * 3 + 2];
        }
        if (tid < 1024) {
            int g = fi1[tid];
            sp1[tid * 3 + 0] = pts[g * 3 + 0];
            sp1[tid * 3 + 1] = pts[g * 3 + 1];
            sp1[tid * 3 + 2] = pts[g * 3 + 2];
        }
        if (tid < 256) {
            int g = fi2[tid];
            sp2[tid * 3 + 0] = pts[g * 3 + 0];
            sp2[tid * 3 + 1] = pts[g * 3 + 1];
            sp2[tid * 3 + 2] = pts[g * 3 + 2];
        }
    } else {
        knn_edge_body(*reinterpret_cast<KnnSmem*>(raw), pts, ew1, eb1, ew2, eb2,
                      feats, blockIdx.x - 1);
    }
}

// ---------------------------------------------------------------------------
// Tail: all three MLPs in one launch (validated mlp numerics, verbatim).
// ---------------------------------------------------------------------------
__device__ __forceinline__ void mlp_body(
    const float* __restrict__ feats, const int* __restrict__ orig,
    const float* __restrict__ mw1, const float* __restrict__ mb1,
    const float* __restrict__ mw2, const float* __restrict__ mb2,
    float* __restrict__ outp, int pb) {
    __shared__ float sfl[64], h1l[128];
    const int t = threadIdx.x;
    for (int pl = 0; pl < 16; ++pl) {
        const int p = pb * 16 + pl;
        const int g = orig[p];
        if (t < 64) sfl[t] = feats[g * 64 + t];
        __syncthreads();
        if (t < 128) {
            float h = mb1[t];
            for (int dd = 0; dd < 64; ++dd)
                h = fmaf(sfl[dd], mw1[dd * 128 + t], h);
            h1l[t] = fmaxf(h, 0.0f);
        }
        __syncthreads();
        float o = mb2[t];
        for (int dd = 0; dd < 128; ++dd)
            o = fmaf(h1l[dd], mw2[dd * 256 + t], o);
        outp[p * 256 + t] = o;
        __syncthreads();
    }
}

__global__ __launch_bounds__(256) void tail_kernel(
    const float* __restrict__ feats,
    const int* __restrict__ fi0, const int* __restrict__ fi1,
    const int* __restrict__ fi2,
    const float* __restrict__ mw1, const float* __restrict__ mb1,
    const float* __restrict__ mw2, const float* __restrict__ mb2,
    float* __restrict__ out) {
    const int b = blockIdx.x;
    float* lf0 = out + 12288;
    float* lf1 = out + 1063936;
    float* lf2 = out + 1326848;
    if (b < 256) {
        mlp_body(feats, fi0, mw1 + 0 * 8192, mb1 + 0 * 128,
                 mw2 + 0 * 32768, mb2 + 0 * 256, lf0, b);
    } else if (b < 320) {
        mlp_body(feats, fi1, mw1 + 1 * 8192, mb1 + 1 * 128,
                 mw2 + 1 * 32768, mb2 + 1 * 256, lf1, b - 256);
    } else {
        mlp_body(feats, fi2, mw1 + 2 * 8192, mb1 + 2 * 128,
                 mw2 + 2 * 32768, mb2 + 2 * 256, lf2, b - 320);
    }
}

// ---------------------------------------------------------------------------
extern "C" void kernel_launch(void* const* d_in, const int* in_sizes, int n_in,
                              void* d_out, int out_size, void* d_ws, size_t ws_size,
                              hipStream_t stream) {
    const float* pts = (const float*)d_in[0];
    const float* ew1 = (const float*)d_in[1];
    const float* eb1 = (const float*)d_in[2];
    const float* ew2 = (const float*)d_in[3];
    const float* eb2 = (const float*)d_in[4];
    const float* mw1 = (const float*)d_in[5];  // (3,64,128)
    const float* mb1 = (const float*)d_in[6];  // (3,128)
    const float* mw2 = (const float*)d_in[7];  // (3,128,256)
    const float* mb2 = (const float*)d_in[8];  // (3,256)
    float* out = (float*)d_out;
    char* ws = (char*)d_ws;

    float* feats = (float*)(ws + 0);           // 16384*64*4 = 4 MB
    int* fi0 = (int*)(ws + 4194304);           // 4096 ints (original indices)
    int* fi1 = (int*)(ws + 4210688);           // 1024 ints (original indices)
    int* fi2 = (int*)(ws + 4214784);           // 256 ints  (original indices)

    float* sp0 = out + 0;
    float* sp1 = out + 1060864;
    float* sp2 = out + 1326080;

    mega_kernel<<<1 + N_PTS / 16, 1024, 0, stream>>>(pts, ew1, eb1, ew2, eb2, feats,
                                                     fi0, fi1, fi2, sp0, sp1, sp2);
    tail_kernel<<<336, 256, 0, stream>>>(feats, fi0, fi1, fi2, mw1, mb1, mw2, mb2, out);
}